// Round 12
// baseline (374.627 us; speedup 1.0000x reference)
//
#include <hip/hip_runtime.h>

typedef __attribute__((ext_vector_type(8))) short bf16x8;
typedef __attribute__((ext_vector_type(4))) float f32x4;

__device__ __forceinline__ float b2f(ushort s) { return __uint_as_float(((uint)s) << 16); }
__device__ __forceinline__ ushort f2b(float f) {
  uint u = __float_as_uint(f);
  u += 0x7fff + ((u >> 16) & 1);   // RNE
  return (ushort)(u >> 16);
}

__device__ __forceinline__ void store_h(float* p, float v) { *p = v; }
__device__ __forceinline__ void store_h(ushort* p, float v) { *p = f2b(v); }

__device__ __forceinline__ float sigm_fast(float x) { return 1.f / (1.f + __expf(-x)); }
__device__ __forceinline__ float tanh_fast(float c) {
  float e = __expf(-2.f * fabsf(c));
  float t = (1.f - e) / (1.f + e);
  return copysignf(t, c);
}

// ---------------- transpose+cast: in (R x C) f32 -> out (C x R) bf16 ----------------
__global__ void transpose_kernel(const float* __restrict__ in, ushort* __restrict__ out,
                                 int R, int C) {
  __shared__ ushort tile[32][33];
  int bc = blockIdx.x << 5;
  int br = blockIdx.y << 5;
  int tx = threadIdx.x & 31;
  int ty = threadIdx.x >> 5;  // 0..7
#pragma unroll
  for (int i = 0; i < 32; i += 8)
    tile[ty + i][tx] = f2b(in[(size_t)(br + ty + i) * C + bc + tx]);
  __syncthreads();
#pragma unroll
  for (int i = 0; i < 32; i += 8)
    out[(size_t)(bc + ty + i) * R + br + tx] = tile[tx][ty + i];
}

// ---------------- embedding gather+cast ----------------
__global__ void embed_kernel(const int* __restrict__ tok, const float* __restrict__ emb,
                             ushort* __restrict__ x) {
  int tid = threadIdx.x;
  int r = (blockIdx.x << 2) + (tid >> 6);
  int c = (tid & 63) << 3;
  int t = tok[r];
  const float* src = emb + ((size_t)t << 9) + c;
  float4 a = *(const float4*)src;
  float4 b = *(const float4*)(src + 4);
  uint4 o;
  o.x = (uint)f2b(a.x) | ((uint)f2b(a.y) << 16);
  o.y = (uint)f2b(a.z) | ((uint)f2b(a.w) << 16);
  o.z = (uint)f2b(b.x) | ((uint)f2b(b.y) << 16);
  o.w = (uint)f2b(b.z) | ((uint)f2b(b.w) << 16);
  *(uint4*)(x + ((size_t)r << 9) + c) = o;
}

// ---------------- GEMM v7: 256x256 tile, BK=32, 4-buffer deep pipeline --------------
// C(MxN) bf16 = A(MxK) * BT(NxK), 512 threads = 8 waves (2M x 4N), per-wave 128x64 out.
// R11 lesson: per-tile vmcnt(0) drain + sched_barrier(0) pins + 2-barriers/phase kept
// the LDS and MFMA pipes fully serialized (tile = 2304+2483+700 cyc, MfmaUtil 39%).
// AITER-shaped loop instead: ONE barrier per K-tile, counted vmcnt(8) (never drains in
// main loop), 3-tile-deep staging into 4 LDS buffers, ~32 MFMA per barrier. Next tile's
// ds_reads issue while this tile's MFMA cluster drains the matrix pipe.
// BK=32 bonus: a ds_read_b128 wave-access covers 16 contiguous 64B rows = 1KB
// contiguous -> inherently bank-conflict-free; NO swizzle, fully linear staging.
// Per tile/wave: 12 ds_read_b128 + 32 MFMA; CU: LDS 1150 cyc vs MFMA 1242 cyc.
__global__ __launch_bounds__(512, 1) void gemm_bt7_kernel(
    const ushort* __restrict__ A, const ushort* __restrict__ BT,
    ushort* __restrict__ C, int M, int N, int K) {
  __shared__ char lds[4][32768];  // per buf: A bytes [0,16384), B bytes [16384,32768)
  const int tid = threadIdx.x;
  const int lane = tid & 63;
  const int wave = tid >> 6;  // 0..7
  const int wr = wave >> 2;   // 0..1
  const int wc = wave & 3;    // 0..3

  // supertile mapping (requires gridDim.x % 256 == 0; true for 1024 and 768)
  const int xcd = blockIdx.x & 7;
  const int l = blockIdx.x >> 3;
  const int s = xcd * (gridDim.x >> 8) + (l >> 5);  // supertile id (8mt x 4nt)
  const int uu = l & 31;
  const int mt = ((s & 7) << 3) + (uu & 7);
  const int nt = ((s >> 3) << 2) + (uu >> 3);
  const int m0 = mt << 8;
  const int n0 = nt << 8;
  const int NT = K >> 5;

  // ds_read bases: rows are 64B (BK=32); a wave's b128 access = 16 rows = 1KB contiguous
  const int aBase = (wr << 13) + ((lane & 15) << 6) + ((lane >> 4) << 4);
  const int bBase = 16384 + (wc << 12) + ((lane & 15) << 6) + ((lane >> 4) << 4);

  // staging source offsets (elements), t-invariant, linear (shared row calc for A/B)
  int srcoff[2];
#pragma unroll
  for (int sub = 0; sub < 2; ++sub) {
    int row = (sub << 7) + (wave << 4) + (lane >> 2);  // 0..255
    srcoff[sub] = row * K + ((lane & 3) << 3);
  }
  const ushort* Abase = A + (size_t)m0 * K;
  const ushort* Bbase = BT + (size_t)n0 * K;

  auto stage = [&](int t, int p) {
    const int tk = t << 5;
#pragma unroll
    for (int i = 0; i < 4; ++i) {
      int sub = i & 1;
      const ushort* src = ((i < 2) ? Abase : Bbase) + srcoff[sub] + tk;
      char* dst = lds[p] + ((i < 2) ? 0 : 16384) + (sub << 13) + (wave << 10);
      __builtin_amdgcn_global_load_lds(
          (const __attribute__((address_space(1))) void*)src,
          (__attribute__((address_space(3))) void*)dst, 16, 0, 0);
    }
  };

  f32x4 acc[8][4];
#pragma unroll
  for (int i = 0; i < 8; ++i)
#pragma unroll
    for (int j = 0; j < 4; ++j) acc[i][j] = (f32x4){0.f, 0.f, 0.f, 0.f};

  // prologue: stage tiles 0,1,2 (12 loads in flight)
  stage(0, 0);
  stage(1, 1);
  stage(2, 2);

  for (int t = 0; t < NT; ++t) {
    // counted wait: tile t's 4 loads arrived; later tiles' loads stay in flight
    if (t < NT - 2) {
      asm volatile("s_waitcnt vmcnt(8)" ::: "memory");
    } else if (t == NT - 2) {
      asm volatile("s_waitcnt vmcnt(4)" ::: "memory");
    } else {
      asm volatile("s_waitcnt vmcnt(0)" ::: "memory");
    }
    __builtin_amdgcn_s_barrier();  // all waves' tile-t data visible; buf (t+3)&3 free
    if (t + 3 < NT) stage(t + 3, (t + 3) & 3);

    const char* base = (const char*)lds[0] + ((t & 3) << 15);
    bf16x8 af[8], bg[4];
    af[0] = *(const bf16x8*)(base + aBase);
#pragma unroll
    for (int ni = 0; ni < 4; ++ni) bg[ni] = *(const bf16x8*)(base + bBase + (ni << 10));
#pragma unroll
    for (int mi = 1; mi < 8; ++mi) af[mi] = *(const bf16x8*)(base + aBase + (mi << 10));
    __builtin_amdgcn_s_setprio(1);
#pragma unroll
    for (int mi = 0; mi < 8; ++mi)
#pragma unroll
      for (int ni = 0; ni < 4; ++ni)
        acc[mi][ni] =
            __builtin_amdgcn_mfma_f32_16x16x32_bf16(af[mi], bg[ni], acc[mi][ni], 0, 0, 0);
    __builtin_amdgcn_s_setprio(0);
    // no closing barrier: next iter's opening barrier orders buf reuse; MFMA drain
    // overlaps next iter's vmcnt/barrier/ds_reads
  }

  // epilogue: D row=(lane>>4)*4+j, col=lane&15
#pragma unroll
  for (int mi = 0; mi < 8; ++mi) {
#pragma unroll
    for (int j = 0; j < 4; ++j) {
      int row = m0 + (wr << 7) + (mi << 4) + ((lane >> 4) << 2) + j;
      size_t bofs = (size_t)row * N + n0 + (wc << 6);
#pragma unroll
      for (int ni = 0; ni < 4; ++ni)
        C[bofs + (ni << 4) + (lane & 15)] = f2b(acc[mi][ni][j]);
    }
  }
}

// ---------------- SRU bidirectional scan ----------------
template <int KC, typename OT>
__global__ void sru_scan_kernel(const ushort* __restrict__ u, const float* __restrict__ bias,
                                const ushort* __restrict__ xres, OT* __restrict__ hout,
                                float* __restrict__ cout) {
  const int L = 256, B = 64, H = 512;
  int idx = blockIdx.x * 256 + threadIdx.x;
  int h = idx & (H - 1);
  int dir = (idx >> 9) & 1;
  int b = idx >> 10;
  float bfg = bias[dir * H + h];
  float brg = bias[2 * H + dir * H + h];
  const size_t ustep = (size_t)B * 2 * H * KC;
  const ushort* ubase = u + ((size_t)b * 2 + dir) * H * KC + (size_t)h * KC;
  const size_t hstep = (size_t)B * 2 * H;
  const size_t hoff = (size_t)b * 2 * H + (size_t)dir * H + h;
  float c = 0.f;
#pragma unroll 16
  for (int s = 0; s < L; ++s) {
    int t = dir ? (L - 1 - s) : s;
    const ushort* up = ubase + (size_t)t * ustep;
    float xt, fg, rg, xr;
    if (KC == 4) {
      uint2 v = *(const uint2*)up;
      xt = b2f((ushort)(v.x & 0xffff));
      fg = b2f((ushort)(v.x >> 16));
      rg = b2f((ushort)(v.y & 0xffff));
      xr = b2f((ushort)(v.y >> 16));
    } else {
      xt = b2f(up[0]);
      fg = b2f(up[1]);
      rg = b2f(up[2]);
      xr = b2f(xres[hoff + (size_t)t * hstep]);
    }
    float f = sigm_fast(fg + bfg);
    float r = sigm_fast(rg + brg);
    c = f * c + (1.f - f) * xt;
    float hv = r * tanh_fast(c) + (1.f - r) * xr;
    store_h(hout + hoff + (size_t)t * hstep, hv);
  }
  cout[(size_t)b * 2 * H + (size_t)dir * H + h] = c;
}

// ---------------- dense_hidden ----------------
__global__ __launch_bounds__(512) void dense_kernel(
    const float* __restrict__ c12, const ushort* __restrict__ WdT,
    const float* __restrict__ bd, float* __restrict__ out) {
  int row = blockIdx.x;
  int j = threadIdx.x;
  const float* c = c12 + (size_t)row * 1024;
  float acc = bd[j];
#pragma unroll 8
  for (int k = 0; k < 1024; ++k) acc += c[k] * b2f(WdT[(size_t)k * 512 + j]);
  out[(size_t)row * 512 + j] = acc;
}

extern "C" void kernel_launch(void* const* d_in, const int* in_sizes, int n_in,
                              void* d_out, int out_size, void* d_ws, size_t ws_size,
                              hipStream_t stream) {
  const int* tok = (const int*)d_in[0];
  const float* emb = (const float*)d_in[1];
  const float* W0 = (const float*)d_in[2];
  const float* b0 = (const float*)d_in[3];
  const float* W1 = (const float*)d_in[4];
  const float* b1 = (const float*)d_in[5];
  const float* Wd = (const float*)d_in[6];
  const float* bd = (const float*)d_in[7];
  float* out = (float*)d_out;

  char* ws = (char*)d_ws;
  ushort* x = (ushort*)ws;                        //  16,777,216 B
  ushort* W0T = (ushort*)(ws + 16777216);         //   4,194,304 B
  ushort* W1T = (ushort*)(ws + 20971520);         //   6,291,456 B
  ushort* u = (ushort*)(ws + 27262976);           // 134,217,728 B (u0/u1 aliased)
  ushort* h1 = (ushort*)(ws + 161480704);         //  33,554,432 B
  float* c12 = (float*)(ws + 195035136);          //     524,288 B
  ushort* WdT = (ushort*)(ws + 27262976 + 100663296);  // dead tail of u after scan1

  transpose_kernel<<<dim3(128, 16), 256, 0, stream>>>(W0, W0T, 512, 4096);
  transpose_kernel<<<dim3(96, 32), 256, 0, stream>>>(W1, W1T, 1024, 3072);
  embed_kernel<<<4096, 256, 0, stream>>>(tok, emb, x);
  // u0 = x @ W0   (16384 x 4096), 64 Mtiles x 16 Ntiles
  gemm_bt7_kernel<<<1024, 512, 0, stream>>>(x, W0T, u, 16384, 4096, 512);
  sru_scan_kernel<4, ushort><<<256, 256, 0, stream>>>(u, b0, (const ushort*)nullptr, h1, c12);
  // u1 = h1 @ W1  (16384 x 3072), 64 x 12
  gemm_bt7_kernel<<<768, 512, 0, stream>>>(h1, W1T, u, 16384, 3072, 1024);
  sru_scan_kernel<3, float><<<256, 256, 0, stream>>>(u, b1, h1, out, c12 + 65536);
  transpose_kernel<<<dim3(32, 16), 256, 0, stream>>>(Wd, WdT, 512, 1024);
  dense_kernel<<<128, 512, 0, stream>>>(c12, WdT, bd, out + 16777216);
}

// Round 13
// 364.241 us; speedup vs baseline: 1.0285x; 1.0285x over previous
//
#include <hip/hip_runtime.h>

typedef __attribute__((ext_vector_type(8))) short bf16x8;
typedef __attribute__((ext_vector_type(4))) float f32x4;

__device__ __forceinline__ float b2f(ushort s) { return __uint_as_float(((uint)s) << 16); }
__device__ __forceinline__ ushort f2b(float f) {
  uint u = __float_as_uint(f);
  u += 0x7fff + ((u >> 16) & 1);   // RNE
  return (ushort)(u >> 16);
}

__device__ __forceinline__ void store_h(float* p, float v) { *p = v; }
__device__ __forceinline__ void store_h(ushort* p, float v) { *p = f2b(v); }

__device__ __forceinline__ float sigm_fast(float x) { return 1.f / (1.f + __expf(-x)); }
__device__ __forceinline__ float tanh_fast(float c) {
  float e = __expf(-2.f * fabsf(c));
  float t = (1.f - e) / (1.f + e);
  return copysignf(t, c);
}

// ---------------- transpose+cast: in (R x C) f32 -> out (C x R) bf16 ----------------
__global__ void transpose_kernel(const float* __restrict__ in, ushort* __restrict__ out,
                                 int R, int C) {
  __shared__ ushort tile[32][33];
  int bc = blockIdx.x << 5;
  int br = blockIdx.y << 5;
  int tx = threadIdx.x & 31;
  int ty = threadIdx.x >> 5;  // 0..7
#pragma unroll
  for (int i = 0; i < 32; i += 8)
    tile[ty + i][tx] = f2b(in[(size_t)(br + ty + i) * C + bc + tx]);
  __syncthreads();
#pragma unroll
  for (int i = 0; i < 32; i += 8)
    out[(size_t)(bc + ty + i) * R + br + tx] = tile[tx][ty + i];
}

// ---------------- embedding gather+cast ----------------
__global__ void embed_kernel(const int* __restrict__ tok, const float* __restrict__ emb,
                             ushort* __restrict__ x) {
  int tid = threadIdx.x;
  int r = (blockIdx.x << 2) + (tid >> 6);
  int c = (tid & 63) << 3;
  int t = tok[r];
  const float* src = emb + ((size_t)t << 9) + c;
  float4 a = *(const float4*)src;
  float4 b = *(const float4*)(src + 4);
  uint4 o;
  o.x = (uint)f2b(a.x) | ((uint)f2b(a.y) << 16);
  o.y = (uint)f2b(a.z) | ((uint)f2b(a.w) << 16);
  o.z = (uint)f2b(b.x) | ((uint)f2b(b.y) << 16);
  o.w = (uint)f2b(b.z) | ((uint)f2b(b.w) << 16);
  *(uint4*)(x + ((size_t)r << 9) + c) = o;
}

// ---------------- GEMM v5 (R10 best-measured: 110.8us, conflicts 0) -----------------
// 256x256 tile, BK=64, 2-buffer counted-vmcnt, explicit frag double-buffer,
// base+immediate ds_reads (4 addr regs), gload_lds w=16 linear dest + inverse-swizzled
// src, XCD-chunked 8x4 supertile mapping.
__global__ __launch_bounds__(512, 1) void gemm_bt5_kernel(
    const ushort* __restrict__ A, const ushort* __restrict__ BT,
    ushort* __restrict__ C, int M, int N, int K) {
  __shared__ char lds[2][65536];  // per buf: A bytes [0,32768), B bytes [32768,65536)
  const int tid = threadIdx.x;
  const int lane = tid & 63;
  const int wave = tid >> 6;  // 0..7
  const int wr = wave >> 2;   // 0..1
  const int wc = wave & 3;    // 0..3

  const int xcd = blockIdx.x & 7;
  const int l = blockIdx.x >> 3;
  const int s = xcd * (gridDim.x >> 8) + (l >> 5);  // supertile id (8mt x 4nt)
  const int uu = l & 31;
  const int mt = ((s & 7) << 3) + (uu & 7);
  const int nt = ((s >> 3) << 2) + (uu >> 3);
  const int m0 = mt << 8;
  const int n0 = nt << 8;
  const int NT = K >> 6;

  const int k0s = ((lane >> 4) << 4) ^ ((lane & 7) << 4);
  const int aB0 = (wr << 14) + ((lane & 15) << 7) + k0s;
  const int aB1 = aB0 ^ 64;
  const int bB0 = 32768 + (wc << 13) + ((lane & 15) << 7) + k0s;
  const int bB1 = bB0 ^ 64;

  int srcoff[4];
#pragma unroll
  for (int sub = 0; sub < 4; ++sub) {
    int off = (sub << 13) + (tid << 4);
    int row = off >> 7;
    int col = ((off & 127) ^ ((row & 7) << 4)) >> 1;
    srcoff[sub] = row * K + col;
  }
  const ushort* Abase = A + (size_t)m0 * K;
  const ushort* Bbase = BT + (size_t)n0 * K;

  auto stage = [&](int t, int p) {
    const int tk = t << 6;
#pragma unroll
    for (int i = 0; i < 8; ++i) {
      int sub = i & 3;
      const ushort* src = ((i < 4) ? Abase : Bbase) + srcoff[sub] + tk;
      char* dst = lds[p] + ((i < 4) ? 0 : 32768) + (sub << 13) + (wave << 10);
      __builtin_amdgcn_global_load_lds(
          (const __attribute__((address_space(1))) void*)src,
          (__attribute__((address_space(3))) void*)dst, 16, 0, 0);
    }
  };

  f32x4 acc[8][4];
#pragma unroll
  for (int i = 0; i < 8; ++i)
#pragma unroll
    for (int j = 0; j < 4; ++j) acc[i][j] = (f32x4){0.f, 0.f, 0.f, 0.f};

  stage(0, 0);
  for (int t = 0; t < NT; ++t) {
    int p = t & 1;
    if (t + 1 < NT) {
      stage(t + 1, p ^ 1);
      asm volatile("s_waitcnt vmcnt(8)" ::: "memory");
    } else {
      asm volatile("s_waitcnt vmcnt(0)" ::: "memory");
    }
    __builtin_amdgcn_s_barrier();
    const char* base = (const char*)lds[0] + (p << 16);
    bf16x8 afA[8], bgA[4], afB[8], bgB[4];
#pragma unroll
    for (int mi = 0; mi < 8; ++mi) afA[mi] = *(const bf16x8*)(base + aB0 + (mi << 11));
#pragma unroll
    for (int ni = 0; ni < 4; ++ni) bgA[ni] = *(const bf16x8*)(base + bB0 + (ni << 11));
#pragma unroll
    for (int mi = 0; mi < 8; ++mi) afB[mi] = *(const bf16x8*)(base + aB1 + (mi << 11));
#pragma unroll
    for (int ni = 0; ni < 4; ++ni) bgB[ni] = *(const bf16x8*)(base + bB1 + (ni << 11));
    __builtin_amdgcn_s_setprio(1);
#pragma unroll
    for (int mi = 0; mi < 8; ++mi)
#pragma unroll
      for (int ni = 0; ni < 4; ++ni)
        acc[mi][ni] =
            __builtin_amdgcn_mfma_f32_16x16x32_bf16(afA[mi], bgA[ni], acc[mi][ni], 0, 0, 0);
#pragma unroll
    for (int mi = 0; mi < 8; ++mi)
#pragma unroll
      for (int ni = 0; ni < 4; ++ni)
        acc[mi][ni] =
            __builtin_amdgcn_mfma_f32_16x16x32_bf16(afB[mi], bgB[ni], acc[mi][ni], 0, 0, 0);
    __builtin_amdgcn_s_setprio(0);
    __builtin_amdgcn_s_barrier();
  }
#pragma unroll
  for (int mi = 0; mi < 8; ++mi) {
#pragma unroll
    for (int j = 0; j < 4; ++j) {
      int row = m0 + (wr << 7) + (mi << 4) + ((lane >> 4) << 2) + j;
      size_t bofs = (size_t)row * N + n0 + (wc << 6);
#pragma unroll
      for (int ni = 0; ni < 4; ++ni)
        C[bofs + (ni << 4) + (lane & 15)] = f2b(acc[mi][ni][j]);
    }
  }
}

// ---------------- SRU chunk-parallel bidirectional scan ----------------
// Old scan: 65536 threads = 1 wave/SIMD, latency-starved (~120us vs ~57us BW floor).
// Affine recurrence c=f*c+g is chunk-decomposable: 8 chunks x 32 steps per channel.
// Block = 32 channels x 8 chunks. Pass1: scan own chunk from c=0, stash per-step
// f,g,r,(1-r)*xr in regs (fully unrolled, static idx), P=prod(f). LDS combine (P,S)
// -> exact chunk entry state c_in. Pass2: replay from c_in — IDENTICAL fma sequence
// to the single-pass scan (same numerics) — write h; chunk 7 writes c_last.
template <int KC, typename OT>
__global__ __launch_bounds__(256, 1) void sru_scan_chunked(
    const ushort* __restrict__ u, const float* __restrict__ bias,
    const ushort* __restrict__ xres, OT* __restrict__ hout, float* __restrict__ cout) {
  const int L = 256, CL = 32;
  __shared__ float Psh[256], Ssh[256];
  const int tid = threadIdx.x;
  const int j = tid >> 5;       // chunk 0..7
  const int chl = tid & 31;     // channel-local
  const int ch = blockIdx.x * 32 + chl;  // global channel = b*1024 + dir*512 + h
  const int h = ch & 511;
  const int dir = (ch >> 9) & 1;
  const float bfg = bias[dir * 512 + h];
  const float brg = bias[1024 + dir * 512 + h];
  const size_t ustep = (size_t)65536 * KC;
  const ushort* ubase = u + (size_t)ch * KC;
  const size_t hstep = 65536;
  const int t0 = dir ? (L - 1 - j * CL) : (j * CL);
  const int tstep = dir ? -1 : 1;

  float fv[CL], gv[CL], rv[CL], rx[CL];
  float c = 0.f, P = 1.f;
#pragma unroll
  for (int s = 0; s < CL; ++s) {
    int t = t0 + s * tstep;
    const ushort* up = ubase + (size_t)t * ustep;
    float xt, fg, rg, xr;
    if (KC == 4) {
      uint2 v = *(const uint2*)up;
      xt = b2f((ushort)(v.x & 0xffff));
      fg = b2f((ushort)(v.x >> 16));
      rg = b2f((ushort)(v.y & 0xffff));
      xr = b2f((ushort)(v.y >> 16));
    } else {
      xt = b2f(up[0]);
      fg = b2f(up[1]);
      rg = b2f(up[2]);
      xr = b2f(xres[ch + (size_t)t * hstep]);
    }
    float f = sigm_fast(fg + bfg);
    float r = sigm_fast(rg + brg);
    fv[s] = f;
    gv[s] = (1.f - f) * xt;
    rv[s] = r;
    rx[s] = (1.f - r) * xr;
    c = f * c + gv[s];
    P *= f;
  }
  Psh[(chl << 3) + j] = P;
  Ssh[(chl << 3) + j] = c;
  __syncthreads();
  float cin = 0.f;
#pragma unroll
  for (int k = 0; k < 7; ++k) {
    if (k < j) cin = Psh[(chl << 3) + k] * cin + Ssh[(chl << 3) + k];
  }
  c = cin;
#pragma unroll
  for (int s = 0; s < CL; ++s) {
    int t = t0 + s * tstep;
    c = fv[s] * c + gv[s];
    float hv = rv[s] * tanh_fast(c) + rx[s];
    store_h(hout + ch + (size_t)t * hstep, hv);
  }
  if (j == 7) cout[ch] = c;  // exact single-pass final state
}

// ---------------- dense_hidden ----------------
__global__ __launch_bounds__(512) void dense_kernel(
    const float* __restrict__ c12, const ushort* __restrict__ WdT,
    const float* __restrict__ bd, float* __restrict__ out) {
  int row = blockIdx.x;
  int j = threadIdx.x;
  const float* c = c12 + (size_t)row * 1024;
  float acc = bd[j];
#pragma unroll 8
  for (int k = 0; k < 1024; ++k) acc += c[k] * b2f(WdT[(size_t)k * 512 + j]);
  out[(size_t)row * 512 + j] = acc;
}

extern "C" void kernel_launch(void* const* d_in, const int* in_sizes, int n_in,
                              void* d_out, int out_size, void* d_ws, size_t ws_size,
                              hipStream_t stream) {
  const int* tok = (const int*)d_in[0];
  const float* emb = (const float*)d_in[1];
  const float* W0 = (const float*)d_in[2];
  const float* b0 = (const float*)d_in[3];
  const float* W1 = (const float*)d_in[4];
  const float* b1 = (const float*)d_in[5];
  const float* Wd = (const float*)d_in[6];
  const float* bd = (const float*)d_in[7];
  float* out = (float*)d_out;

  char* ws = (char*)d_ws;
  ushort* x = (ushort*)ws;                        //  16,777,216 B
  ushort* W0T = (ushort*)(ws + 16777216);         //   4,194,304 B
  ushort* W1T = (ushort*)(ws + 20971520);         //   6,291,456 B
  ushort* u = (ushort*)(ws + 27262976);           // 134,217,728 B (u0/u1 aliased)
  ushort* h1 = (ushort*)(ws + 161480704);         //  33,554,432 B
  float* c12 = (float*)(ws + 195035136);          //     524,288 B
  ushort* WdT = (ushort*)(ws + 27262976 + 100663296);  // dead tail of u after scan1

  transpose_kernel<<<dim3(128, 16), 256, 0, stream>>>(W0, W0T, 512, 4096);
  transpose_kernel<<<dim3(96, 32), 256, 0, stream>>>(W1, W1T, 1024, 3072);
  embed_kernel<<<4096, 256, 0, stream>>>(tok, emb, x);
  // u0 = x @ W0   (16384 x 4096)
  gemm_bt5_kernel<<<1024, 512, 0, stream>>>(x, W0T, u, 16384, 4096, 512);
  sru_scan_chunked<4, ushort><<<2048, 256, 0, stream>>>(u, b0, (const ushort*)nullptr, h1, c12);
  // u1 = h1 @ W1  (16384 x 3072)
  gemm_bt5_kernel<<<768, 512, 0, stream>>>(h1, W1T, u, 16384, 3072, 1024);
  sru_scan_chunked<3, float><<<2048, 256, 0, stream>>>(u, b1, h1, out, c12 + 65536);
  transpose_kernel<<<dim3(32, 16), 256, 0, stream>>>(Wd, WdT, 512, 1024);
  dense_kernel<<<128, 512, 0, stream>>>(c12, WdT, bd, out + 16777216);
}